// Round 8
// baseline (184.149 us; speedup 1.0000x reference)
//
#include <hip/hip_runtime.h>

#define MARGIN 0.3f

typedef __attribute__((ext_vector_type(8))) short short8;
typedef __attribute__((ext_vector_type(4))) float floatx4;

// ---- helpers ----------------------------------------------------------------

// order-preserving float->uint encoding so unsigned atomicMin == float min
__device__ __forceinline__ unsigned enc_f32(float f) {
    unsigned u = __float_as_uint(f);
    return (u & 0x80000000u) ? ~u : (u | 0x80000000u);
}
__device__ __forceinline__ float dec_f32(unsigned u) {
    return (u & 0x80000000u) ? __uint_as_float(u & 0x7fffffffu)
                             : __uint_as_float(~u);
}
// fp32 -> bf16 bits, round-to-nearest-even
__device__ __forceinline__ short f2bf(float f) {
    unsigned u = __float_as_uint(f);
    u = u + 0x7fffu + ((u >> 16) & 1u);
    return (short)(u >> 16);
}

// Fragment-native global layout: element (row, k) with g16=row/16, r=row%16,
// kk=k/32, q=(k%32)/8, e=k%8 lives at  g16*2048 + kk*512 + q*128 + r*8 + e.
// One wave fragment load = base + lane*8 shorts = 64 lanes x 16 B contiguous.

// ---- kernel 1: prepass ------------------------------------------------------
// grid n/16 x 256. Thread h: row = h/16, part p = h%16 -> (kk=p/4, q=p%4):
// two consecutive float4 loads, one 16 B store into fragment layout. Also
// exact fp32 sq1/sq2/posd (16-lane shuffle reduce) and inits.
__global__ void prep_kernel(const float* __restrict__ z1, const float* __restrict__ z2,
                            short* __restrict__ z1b, short* __restrict__ z2b,
                            float* __restrict__ sq1, float* __restrict__ sq2,
                            float* __restrict__ posd, unsigned* __restrict__ rowmin,
                            unsigned* __restrict__ cnt, float* __restrict__ out) {
    int h = blockIdx.x * 256 + threadIdx.x;     // 0 .. n*16-1
    int row = h >> 4, p = h & 15;
    int kk = p >> 2, q = p & 3;
    int f0 = row * 32 + kk * 8 + q * 2;         // first float4 index
    float4 fa0 = ((const float4*)z1)[f0], fa1 = ((const float4*)z1)[f0 + 1];
    float4 fb0 = ((const float4*)z2)[f0], fb1 = ((const float4*)z2)[f0 + 1];
    short8 sa = { f2bf(fa0.x), f2bf(fa0.y), f2bf(fa0.z), f2bf(fa0.w),
                  f2bf(fa1.x), f2bf(fa1.y), f2bf(fa1.z), f2bf(fa1.w) };
    short8 sb = { f2bf(fb0.x), f2bf(fb0.y), f2bf(fb0.z), f2bf(fb0.w),
                  f2bf(fb1.x), f2bf(fb1.y), f2bf(fb1.z), f2bf(fb1.w) };
    size_t off = (size_t)(row >> 4) * 2048 + kk * 512 + q * 128 + (row & 15) * 8;
    *(short8*)&z1b[off] = sa;
    *(short8*)&z2b[off] = sb;

    float s1 = fa0.x*fa0.x + fa0.y*fa0.y + fa0.z*fa0.z + fa0.w*fa0.w
             + fa1.x*fa1.x + fa1.y*fa1.y + fa1.z*fa1.z + fa1.w*fa1.w;
    float s2 = fb0.x*fb0.x + fb0.y*fb0.y + fb0.z*fb0.z + fb0.w*fb0.w
             + fb1.x*fb1.x + fb1.y*fb1.y + fb1.z*fb1.z + fb1.w*fb1.w;
    float dx0 = fa0.x-fb0.x, dy0 = fa0.y-fb0.y, dz0 = fa0.z-fb0.z, dw0 = fa0.w-fb0.w;
    float dx1 = fa1.x-fb1.x, dy1 = fa1.y-fb1.y, dz1 = fa1.z-fb1.z, dw1 = fa1.w-fb1.w;
    float p2 = dx0*dx0 + dy0*dy0 + dz0*dz0 + dw0*dw0
             + dx1*dx1 + dy1*dy1 + dz1*dz1 + dw1*dw1;
    #pragma unroll
    for (int m = 8; m >= 1; m >>= 1) {          // 16 threads per row
        s1 += __shfl_xor(s1, m);
        s2 += __shfl_xor(s2, m);
        p2 += __shfl_xor(p2, m);
    }
    if (p == 0) { sq1[row] = s1; sq2[row] = s2; posd[row] = sqrtf(p2); }

    if (threadIdx.x < 16) rowmin[blockIdx.x * 16 + threadIdx.x] = 0xFFFFFFFFu;
    if (blockIdx.x == 0) {
        if (threadIdx.x < 64) cnt[threadIdx.x] = 0u;
        if (threadIdx.x == 0) out[0] = 0.0f;
    }
}

// ---- kernel 2: barrier-free register GEMM + row-min + fused loss ------------
// grid (16, 64): rg = 128-row group (4 waves x 32 rows), cgi = 512-col group
// (32 tiles of 16 cols). 1024 blocks = 4/CU (all resident). No LDS staging,
// no __syncthreads in the loop. Per-wave regs ~96 (no spill: R7's 190-reg
// footprint spilled vmin to scratch -> 12 MB scratch traffic, 7.7k cyc/iter).
__global__ __launch_bounds__(256, 4)
void gemm_min_kernel(const short* __restrict__ z1b, const short* __restrict__ z2b,
                     const float* __restrict__ sq1, const float* __restrict__ sq2,
                     const float* __restrict__ posd,
                     unsigned* __restrict__ rowmin, unsigned* __restrict__ cnt,
                     float* __restrict__ out, int n)
{
    __shared__ float lsum[2];
    __shared__ int   fin_s;

    const int rg = blockIdx.y, cgi = blockIdx.x;
    const int tid = threadIdx.x, w = tid >> 6, lane = tid & 63;
    const int quad = lane >> 4, l15 = lane & 15;
    const int rowbase = rg * 128 + w * 32;      // this wave's 32 rows
    const int colorig = cgi * 512;

    // persistent A fragments (coalesced 1 KB loads): af[sm][kk]
    short8 af[2][4];
    #pragma unroll
    for (int sm = 0; sm < 2; ++sm) {
        const short* pa = z1b + (size_t)(rg * 8 + w * 2 + sm) * 2048 + lane * 8;
        #pragma unroll
        for (int kk = 0; kk < 4; ++kk)
            af[sm][kk] = *(const short8*)(pa + kk * 512);
    }

    float vmin[2][4];
    #pragma unroll
    for (int sm = 0; sm < 2; ++sm)
        #pragma unroll
        for (int reg = 0; reg < 4; ++reg)
            vmin[sm][reg] = 3.0e38f;

    short8 bb[2][4];                            // [buf][kk] register dbuf, 16 cols
    {
        const short* pb = z2b + (size_t)(cgi * 32) * 2048 + lane * 8;
        #pragma unroll
        for (int kk = 0; kk < 4; ++kk)
            bb[0][kk] = *(const short8*)(pb + kk * 512);
    }

    #pragma unroll
    for (int t = 0; t < 32; ++t) {
        if (t < 31) {                           // prefetch next 16-col tile
            const short* pb = z2b + (size_t)(cgi * 32 + t + 1) * 2048 + lane * 8;
            #pragma unroll
            for (int kk = 0; kk < 4; ++kk)
                bb[(t + 1) & 1][kk] = *(const short8*)(pb + kk * 512);
        }
        const int colbase = colorig + t * 16;
        const float s2v = sq2[colbase + l15];

        floatx4 acc[2];
        acc[0] = (floatx4)0.0f;
        acc[1] = (floatx4)0.0f;

        #pragma unroll
        for (int kk = 0; kk < 4; ++kk) {
            acc[0] = __builtin_amdgcn_mfma_f32_16x16x32_bf16(af[0][kk], bb[t & 1][kk], acc[0], 0, 0, 0);
            acc[1] = __builtin_amdgcn_mfma_f32_16x16x32_bf16(af[1][kk], bb[t & 1][kk], acc[1], 0, 0, 0);
        }

        // fold v = sq2[j] - 2*dot; diagonal mask only if tiles overlap
        if (colbase < rowbase + 32 && rowbase < colbase + 16) {   // wave-uniform
            #pragma unroll
            for (int sm = 0; sm < 2; ++sm)
                #pragma unroll
                for (int reg = 0; reg < 4; ++reg) {
                    int gi = rowbase + sm * 16 + quad * 4 + reg;  // C/D: col=l15, row=quad*4+reg
                    float v = fmaf(-2.0f, acc[sm][reg], s2v);
                    v = (gi == colbase + l15) ? 3.0e38f : v;
                    vmin[sm][reg] = fminf(vmin[sm][reg], v);
                }
        } else {
            #pragma unroll
            for (int sm = 0; sm < 2; ++sm)
                #pragma unroll
                for (int reg = 0; reg < 4; ++reg)
                    vmin[sm][reg] = fminf(vmin[sm][reg],
                                          fmaf(-2.0f, acc[sm][reg], s2v));
        }
    }

    // min across each quad's 16 lanes, one atomicMin per row per block
    #pragma unroll
    for (int sm = 0; sm < 2; ++sm)
        #pragma unroll
        for (int reg = 0; reg < 4; ++reg) {
            float vm = vmin[sm][reg];
            #pragma unroll
            for (int m = 8; m >= 1; m >>= 1)
                vm = fminf(vm, __shfl_xor(vm, m));
            if (l15 == 0)
                atomicMin(&rowmin[rowbase + sm * 16 + quad * 4 + reg], enc_f32(vm));
        }

    __syncthreads();
    if (tid == 0) {
        __threadfence();    // release: this block's mins visible before bump
        fin_s = (atomicAdd(&cnt[rg], 1u) == 15u);
    }
    __syncthreads();
    if (!fin_s) return;
    __threadfence();        // acquire: see all 16 blocks' mins

    // fused loss for rows [rg*128, rg*128+128): thread = one row (waves 0,1)
    if (tid < 128) {
        int i = rg * 128 + tid;
        unsigned rm = atomicMin(&rowmin[i], 0xFFFFFFFFu);   // coherent forced read
        float hard = sqrtf(fmaxf(sq1[i] + dec_f32(rm), 0.0f));
        float l = fmaxf(posd[i] - hard + MARGIN, 0.0f);
        #pragma unroll
        for (int m = 32; m >= 1; m >>= 1) l += __shfl_xor(l, m);
        if (lane == 0) lsum[w] = l;
    }
    __syncthreads();
    if (tid == 0)
        atomicAdd(out, (lsum[0] + lsum[1]) / (float)n);
}

// ---- launch -----------------------------------------------------------------
extern "C" void kernel_launch(void* const* d_in, const int* in_sizes, int n_in,
                              void* d_out, int out_size, void* d_ws, size_t ws_size,
                              hipStream_t stream) {
    const float* z1 = (const float*)d_in[0];
    const float* z2 = (const float*)d_in[1];
    const int n = in_sizes[0] / 128;            // 8192

    char* ws = (char*)d_ws;
    short*    z1b    = (short*)ws;                                     // 2 MB
    short*    z2b    = (short*)(ws + (size_t)n * 128 * 2);             // 2 MB
    float*    sq1    = (float*)(ws + (size_t)n * 128 * 4);             // 32 KB
    float*    sq2    = (float*)(ws + (size_t)n * 128 * 4 + n * 4);     // 32 KB
    float*    posd   = (float*)(ws + (size_t)n * 128 * 4 + n * 8);     // 32 KB
    unsigned* rowmin = (unsigned*)(ws + (size_t)n * 128 * 4 + n * 12); // 32 KB
    unsigned* cnt    = (unsigned*)(ws + (size_t)n * 128 * 4 + n * 16); // 256 B
    float*    out    = (float*)d_out;

    prep_kernel<<<n / 16, 256, 0, stream>>>(z1, z2, z1b, z2b, sq1, sq2, posd,
                                            rowmin, cnt, out);
    dim3 grid(16, n / 128);                     // (colgroups, rowgroups)
    gemm_min_kernel<<<grid, 256, 0, stream>>>(z1b, z2b, sq1, sq2, posd,
                                              rowmin, cnt, out, n);
}

// Round 9
// 116.234 us; speedup vs baseline: 1.5843x; 1.5843x over previous
//
#include <hip/hip_runtime.h>

#define MARGIN 0.3f

typedef __attribute__((ext_vector_type(8))) short short8;
typedef __attribute__((ext_vector_type(4))) float floatx4;

// ---- helpers ----------------------------------------------------------------

// order-preserving float->uint encoding so unsigned atomicMin == float min
__device__ __forceinline__ unsigned enc_f32(float f) {
    unsigned u = __float_as_uint(f);
    return (u & 0x80000000u) ? ~u : (u | 0x80000000u);
}
__device__ __forceinline__ float dec_f32(unsigned u) {
    return (u & 0x80000000u) ? __uint_as_float(u & 0x7fffffffu)
                             : __uint_as_float(~u);
}
// fp32 -> bf16 bits, round-to-nearest-even
__device__ __forceinline__ short f2bf(float f) {
    unsigned u = __float_as_uint(f);
    u = u + 0x7fffu + ((u >> 16) & 1u);
    return (short)(u >> 16);
}

// Fragment-native global layout: element (row, k) with g16=row/16, r=row%16,
// kk=k/32, q=(k%32)/8, e=k%8 lives at  g16*2048 + kk*512 + q*128 + r*8 + e.
// One wave fragment load = base + lane*8 shorts = 64 lanes x 16 B contiguous.

// ---- kernel 1: prepass ------------------------------------------------------
__global__ void prep_kernel(const float* __restrict__ z1, const float* __restrict__ z2,
                            short* __restrict__ z1b, short* __restrict__ z2b,
                            float* __restrict__ sq1, float* __restrict__ sq2,
                            float* __restrict__ posd, unsigned* __restrict__ rowmin,
                            unsigned* __restrict__ cnt, float* __restrict__ out) {
    int h = blockIdx.x * 256 + threadIdx.x;     // 0 .. n*16-1
    int row = h >> 4, p = h & 15;
    int kk = p >> 2, q = p & 3;
    int f0 = row * 32 + kk * 8 + q * 2;         // first float4 index
    float4 fa0 = ((const float4*)z1)[f0], fa1 = ((const float4*)z1)[f0 + 1];
    float4 fb0 = ((const float4*)z2)[f0], fb1 = ((const float4*)z2)[f0 + 1];
    short8 sa = { f2bf(fa0.x), f2bf(fa0.y), f2bf(fa0.z), f2bf(fa0.w),
                  f2bf(fa1.x), f2bf(fa1.y), f2bf(fa1.z), f2bf(fa1.w) };
    short8 sb = { f2bf(fb0.x), f2bf(fb0.y), f2bf(fb0.z), f2bf(fb0.w),
                  f2bf(fb1.x), f2bf(fb1.y), f2bf(fb1.z), f2bf(fb1.w) };
    size_t off = (size_t)(row >> 4) * 2048 + kk * 512 + q * 128 + (row & 15) * 8;
    *(short8*)&z1b[off] = sa;
    *(short8*)&z2b[off] = sb;

    float s1 = fa0.x*fa0.x + fa0.y*fa0.y + fa0.z*fa0.z + fa0.w*fa0.w
             + fa1.x*fa1.x + fa1.y*fa1.y + fa1.z*fa1.z + fa1.w*fa1.w;
    float s2 = fb0.x*fb0.x + fb0.y*fb0.y + fb0.z*fb0.z + fb0.w*fb0.w
             + fb1.x*fb1.x + fb1.y*fb1.y + fb1.z*fb1.z + fb1.w*fb1.w;
    float dx0 = fa0.x-fb0.x, dy0 = fa0.y-fb0.y, dz0 = fa0.z-fb0.z, dw0 = fa0.w-fb0.w;
    float dx1 = fa1.x-fb1.x, dy1 = fa1.y-fb1.y, dz1 = fa1.z-fb1.z, dw1 = fa1.w-fb1.w;
    float p2 = dx0*dx0 + dy0*dy0 + dz0*dz0 + dw0*dw0
             + dx1*dx1 + dy1*dy1 + dz1*dz1 + dw1*dw1;
    #pragma unroll
    for (int m = 8; m >= 1; m >>= 1) {          // 16 threads per row
        s1 += __shfl_xor(s1, m);
        s2 += __shfl_xor(s2, m);
        p2 += __shfl_xor(p2, m);
    }
    if (p == 0) { sq1[row] = s1; sq2[row] = s2; posd[row] = sqrtf(p2); }

    if (threadIdx.x < 16) rowmin[blockIdx.x * 16 + threadIdx.x] = 0xFFFFFFFFu;
    if (blockIdx.x == 0) {
        if (threadIdx.x < 64) cnt[threadIdx.x] = 0u;
        if (threadIdx.x == 0) out[0] = 0.0f;
    }
}

// ---- kernel 2: barrier-free register GEMM + row-min + fused loss ------------
// grid (16, 64): rg = 128-row group (4 waves x 32 rows), cgi = 512-col group
// (32 tiles of 16 cols). launch_bounds(256,2): this toolchain allocates
// 512/(2*arg2) VGPRs — arg2=2 -> 128-reg ceiling, our ~96-reg footprint fits
// with NO spill (arg2=4 gave a 64-reg cap and 123 MB of scratch traffic, R8).
__global__ __launch_bounds__(256, 2)
void gemm_min_kernel(const short* __restrict__ z1b, const short* __restrict__ z2b,
                     const float* __restrict__ sq1, const float* __restrict__ sq2,
                     const float* __restrict__ posd,
                     unsigned* __restrict__ rowmin, unsigned* __restrict__ cnt,
                     float* __restrict__ out, int n)
{
    __shared__ float lsum[2];
    __shared__ int   fin_s;

    const int rg = blockIdx.y, cgi = blockIdx.x;
    const int tid = threadIdx.x, w = tid >> 6, lane = tid & 63;
    const int quad = lane >> 4, l15 = lane & 15;
    const int rowbase = rg * 128 + w * 32;      // this wave's 32 rows
    const int colorig = cgi * 512;

    // persistent A fragments (coalesced 1 KB loads): af[sm][kk]
    short8 af[2][4];
    #pragma unroll
    for (int sm = 0; sm < 2; ++sm) {
        const short* pa = z1b + (size_t)(rg * 8 + w * 2 + sm) * 2048 + lane * 8;
        #pragma unroll
        for (int kk = 0; kk < 4; ++kk)
            af[sm][kk] = *(const short8*)(pa + kk * 512);
    }

    float vmin[2][4];
    #pragma unroll
    for (int sm = 0; sm < 2; ++sm)
        #pragma unroll
        for (int reg = 0; reg < 4; ++reg)
            vmin[sm][reg] = 3.0e38f;

    short8 bb[2][4];                            // [buf][kk] register dbuf, 16 cols
    {
        const short* pb = z2b + (size_t)(cgi * 32) * 2048 + lane * 8;
        #pragma unroll
        for (int kk = 0; kk < 4; ++kk)
            bb[0][kk] = *(const short8*)(pb + kk * 512);
    }

    #pragma unroll 2
    for (int t = 0; t < 32; ++t) {
        if (t < 31) {                           // prefetch next 16-col tile
            const short* pb = z2b + (size_t)(cgi * 32 + t + 1) * 2048 + lane * 8;
            #pragma unroll
            for (int kk = 0; kk < 4; ++kk)
                bb[(t + 1) & 1][kk] = *(const short8*)(pb + kk * 512);
        }
        const int colbase = colorig + t * 16;
        const float s2v = sq2[colbase + l15];

        floatx4 acc[2];
        acc[0] = (floatx4)0.0f;
        acc[1] = (floatx4)0.0f;

        #pragma unroll
        for (int kk = 0; kk < 4; ++kk) {
            acc[0] = __builtin_amdgcn_mfma_f32_16x16x32_bf16(af[0][kk], bb[t & 1][kk], acc[0], 0, 0, 0);
            acc[1] = __builtin_amdgcn_mfma_f32_16x16x32_bf16(af[1][kk], bb[t & 1][kk], acc[1], 0, 0, 0);
        }

        // fold v = sq2[j] - 2*dot; diagonal mask only if tiles overlap
        if (colbase < rowbase + 32 && rowbase < colbase + 16) {   // wave-uniform
            #pragma unroll
            for (int sm = 0; sm < 2; ++sm)
                #pragma unroll
                for (int reg = 0; reg < 4; ++reg) {
                    int gi = rowbase + sm * 16 + quad * 4 + reg;  // C/D: col=l15, row=quad*4+reg
                    float v = fmaf(-2.0f, acc[sm][reg], s2v);
                    v = (gi == colbase + l15) ? 3.0e38f : v;
                    vmin[sm][reg] = fminf(vmin[sm][reg], v);
                }
        } else {
            #pragma unroll
            for (int sm = 0; sm < 2; ++sm)
                #pragma unroll
                for (int reg = 0; reg < 4; ++reg)
                    vmin[sm][reg] = fminf(vmin[sm][reg],
                                          fmaf(-2.0f, acc[sm][reg], s2v));
        }
    }

    // min across each quad's 16 lanes, one atomicMin per row per block
    #pragma unroll
    for (int sm = 0; sm < 2; ++sm)
        #pragma unroll
        for (int reg = 0; reg < 4; ++reg) {
            float vm = vmin[sm][reg];
            #pragma unroll
            for (int m = 8; m >= 1; m >>= 1)
                vm = fminf(vm, __shfl_xor(vm, m));
            if (l15 == 0)
                atomicMin(&rowmin[rowbase + sm * 16 + quad * 4 + reg], enc_f32(vm));
        }

    __syncthreads();
    if (tid == 0) {
        __threadfence();    // release: this block's mins visible before bump
        fin_s = (atomicAdd(&cnt[rg], 1u) == 15u);
    }
    __syncthreads();
    if (!fin_s) return;
    __threadfence();        // acquire: see all 16 blocks' mins

    // fused loss for rows [rg*128, rg*128+128): thread = one row (waves 0,1)
    if (tid < 128) {
        int i = rg * 128 + tid;
        unsigned rm = atomicMin(&rowmin[i], 0xFFFFFFFFu);   // coherent forced read
        float hard = sqrtf(fmaxf(sq1[i] + dec_f32(rm), 0.0f));
        float l = fmaxf(posd[i] - hard + MARGIN, 0.0f);
        #pragma unroll
        for (int m = 32; m >= 1; m >>= 1) l += __shfl_xor(l, m);
        if (lane == 0) lsum[w] = l;
    }
    __syncthreads();
    if (tid == 0)
        atomicAdd(out, (lsum[0] + lsum[1]) / (float)n);
}

// ---- launch -----------------------------------------------------------------
extern "C" void kernel_launch(void* const* d_in, const int* in_sizes, int n_in,
                              void* d_out, int out_size, void* d_ws, size_t ws_size,
                              hipStream_t stream) {
    const float* z1 = (const float*)d_in[0];
    const float* z2 = (const float*)d_in[1];
    const int n = in_sizes[0] / 128;            // 8192

    char* ws = (char*)d_ws;
    short*    z1b    = (short*)ws;                                     // 2 MB
    short*    z2b    = (short*)(ws + (size_t)n * 128 * 2);             // 2 MB
    float*    sq1    = (float*)(ws + (size_t)n * 128 * 4);             // 32 KB
    float*    sq2    = (float*)(ws + (size_t)n * 128 * 4 + n * 4);     // 32 KB
    float*    posd   = (float*)(ws + (size_t)n * 128 * 4 + n * 8);     // 32 KB
    unsigned* rowmin = (unsigned*)(ws + (size_t)n * 128 * 4 + n * 12); // 32 KB
    unsigned* cnt    = (unsigned*)(ws + (size_t)n * 128 * 4 + n * 16); // 256 B
    float*    out    = (float*)d_out;

    prep_kernel<<<n / 16, 256, 0, stream>>>(z1, z2, z1b, z2b, sq1, sq2, posd,
                                            rowmin, cnt, out);
    dim3 grid(16, n / 128);                     // (colgroups, rowgroups)
    gemm_min_kernel<<<grid, 256, 0, stream>>>(z1b, z2b, sq1, sq2, posd,
                                              rowmin, cnt, out, n);
}